// Round 1
// baseline (178.752 us; speedup 1.0000x reference)
//
#include <hip/hip_runtime.h>
#include <cmath>

// Shapes (fixed for this problem)
#define B_    2
#define N_    6
#define D_    128
#define Q_    2304      // 48*48
#define K_    576       // 24*24
#define NK_   3456      // N_*K_
#define HEADS_ 4
#define DH_   32
#define SCALE_ 0.17677669529663687f        // 1/sqrt(32)
#define SCLOG2E_ 0.25504672615621814f      // SCALE * log2(e)

typedef __attribute__((ext_vector_type(8))) short bf16x8;
typedef __attribute__((ext_vector_type(4))) float f32x4;

#if defined(__has_builtin)
#if __has_builtin(__builtin_amdgcn_cvt_pk_bf16_f32)
#define HAS_PK_BF16 1
#endif
#endif

static __device__ __forceinline__ unsigned short f2bf(float f) {
  union { float f; unsigned u; } x; x.f = f;
  unsigned u = x.u + 0x7fffu + ((x.u >> 16) & 1u);   // RNE
  return (unsigned short)(u >> 16);
}
static __device__ __forceinline__ unsigned pkbf(float a, float b) {
#ifdef HAS_PK_BF16
  typedef __attribute__((ext_vector_type(2))) __bf16 vbf2;
  union { vbf2 v; unsigned u; } cv;
  cv.v = __builtin_amdgcn_cvt_pk_bf16_f32(a, b);   // RNE pack, 1 inst
  return cv.u;
#else
  return (unsigned)f2bf(a) | ((unsigned)f2bf(b) << 16);
#endif
}

// permlane swaps (gfx950): both operands are read-modify-write.
// v_permlane32_swap_b32: dst lanes 32-63 <-> src lanes 0-31
// v_permlane16_swap_b32: dst lanes 16-31 <-> src lanes 0-15,
//                        dst lanes 48-63 <-> src lanes 32-47
static __device__ __forceinline__ void pl32sw(unsigned &a, unsigned &b) {
  asm("v_permlane32_swap_b32 %0, %1" : "+v"(a), "+v"(b));
}
static __device__ __forceinline__ void pl16sw(unsigned &a, unsigned &b) {
  asm("v_permlane16_swap_b32 %0, %1" : "+v"(a), "+v"(b));
}

// ---------------------------------------------------------------------------
// Kernel P: transpose+convert all weights to bf16 WT[n][k] (MFMA B-frag
// layout). 128 blocks, one 32x32 tile each.
// ---------------------------------------------------------------------------
__global__ __launch_bounds__(256) void k_prep_wt(
    const float* __restrict__ Wq, const float* __restrict__ Wk,
    const float* __restrict__ Wv, const float* __restrict__ Wp,
    const float* __restrict__ W1, const float* __restrict__ W2,
    unsigned short* __restrict__ WTq, unsigned short* __restrict__ WTk,
    unsigned short* __restrict__ WTv, unsigned short* __restrict__ WTp,
    unsigned short* __restrict__ WT1, unsigned short* __restrict__ WT2)
{
  __shared__ float tile[32][33];
  const int wb = blockIdx.x, t = threadIdx.x;
  const float* src; unsigned short* dst; int Kd, J, tl;
  if      (wb < 16) { src = Wq; dst = WTq; Kd = 128; J = 128; tl = wb; }
  else if (wb < 32) { src = Wk; dst = WTk; Kd = 128; J = 128; tl = wb - 16; }
  else if (wb < 48) { src = Wv; dst = WTv; Kd = 128; J = 128; tl = wb - 32; }
  else if (wb < 64) { src = Wp; dst = WTp; Kd = 128; J = 128; tl = wb - 48; }
  else if (wb < 96) { src = W1; dst = WT1; Kd = 128; J = 256; tl = wb - 64; }
  else              { src = W2; dst = WT2; Kd = 256; J = 128; tl = wb - 96; }
  const int njt = J >> 5;
  const int tj = tl % njt, tk = tl / njt;
#pragma unroll
  for (int i = 0; i < 4; ++i) {
    int idx = t + 256 * i;
    int r = idx >> 5, c = idx & 31;
    tile[r][c] = src[(size_t)(tk * 32 + r) * J + tj * 32 + c];
  }
  __syncthreads();
#pragma unroll
  for (int i = 0; i < 2; ++i) {
    int idx = t + 256 * i;               // 512 pairs
    int rr = idx >> 4, c2 = (idx & 15) << 1;
    *(unsigned*)&dst[(size_t)(tj * 32 + rr) * Kd + tk * 32 + c2] =
        pkbf(tile[c2][rr], tile[c2 + 1][rr]);
  }
}

// ---------------------------------------------------------------------------
// Kernel A: fused q/k/v LN + MFMA projection (single dispatch, 1296 blocks).
// Q output is pre-scaled by SCALE*log2(e) so attention uses native exp2.
// ---------------------------------------------------------------------------
__global__ __launch_bounds__(256) void k_ln_proj_all(
    const float* __restrict__ qin, const float* __restrict__ kin,
    const float* __restrict__ vin,
    const float* __restrict__ lnq_g, const float* __restrict__ lnq_b,
    const float* __restrict__ lnk_g, const float* __restrict__ lnk_b,
    const float* __restrict__ lnv_g, const float* __restrict__ lnv_b,
    const unsigned short* __restrict__ WTq, const unsigned short* __restrict__ WTk,
    const unsigned short* __restrict__ WTv,
    const float* __restrict__ bq, const float* __restrict__ bk,
    const float* __restrict__ bv,
    unsigned short* __restrict__ QPh, unsigned short* __restrict__ KPh,
    unsigned short* __restrict__ VPTh)
{
  __shared__ float xs[32][132];
  __shared__ unsigned short xh[32][136];
  __shared__ float gs[128], bs[128];
  __shared__ float mu[32], rsd[32];
  const int t = threadIdx.x;
  const int bid = blockIdx.x;

  const float* x; const unsigned short* WT; const float* g; const float* bl;
  const float* bias; int S, blk, mode; float osc;
  if (bid < 864)       { mode = 0; blk = bid;        x = qin; WT = WTq; g = lnq_g; bl = lnq_b; bias = bq; S = Q_; osc = SCLOG2E_; }
  else if (bid < 1080) { mode = 0; blk = bid - 864;  x = kin; WT = WTk; g = lnk_g; bl = lnk_b; bias = bk; S = K_; osc = 1.0f; }
  else                 { mode = 1; blk = bid - 1080; x = vin; WT = WTv; g = lnv_g; bl = lnv_b; bias = bv; S = K_; osc = 1.0f; }
  const int ntile = S >> 5;
  const int o  = blk / ntile;
  const int s0 = (blk % ntile) << 5;

  if (t < 128) { gs[t] = g[t]; bs[t] = bl[t]; }
  const float* xb = x + (size_t)o * 128 * (size_t)S + s0;
#pragma unroll
  for (int i = 0; i < 4; ++i) {
    int idx = t + 256 * i;
    int c = idx >> 3, s4 = (idx & 7) << 2;
    float4 xv = *(const float4*)&xb[(size_t)c * S + s4];
    xs[s4 + 0][c] = xv.x; xs[s4 + 1][c] = xv.y;
    xs[s4 + 2][c] = xv.z; xs[s4 + 3][c] = xv.w;
  }
  __syncthreads();
  {
    int s = t >> 3, l8 = t & 7;
    float sum = 0.f, sq = 0.f;
    for (int c = l8; c < 128; c += 8) { float v = xs[s][c]; sum += v; sq += v * v; }
#pragma unroll
    for (int off = 4; off > 0; off >>= 1) {
      sum += __shfl_down(sum, off, 8);
      sq  += __shfl_down(sq,  off, 8);
    }
    if (l8 == 0) {
      float mth = sum * 0.0078125f;
      float var = sq * 0.0078125f - mth * mth;
      mu[s] = mth; rsd[s] = rsqrtf(var + 1e-5f);
    }
  }
  __syncthreads();
#pragma unroll
  for (int i = 0; i < 8; ++i) {
    int idx = t + 256 * i;               // 2048 pairs
    int s = idx >> 6, c2 = (idx & 63) << 1;
    float y0 = (xs[s][c2]     - mu[s]) * rsd[s] * gs[c2]     + bs[c2];
    float y1 = (xs[s][c2 + 1] - mu[s]) * rsd[s] * gs[c2 + 1] + bs[c2 + 1];
    *(unsigned*)&xh[s][c2] = pkbf(y0, y1);
  }
  __syncthreads();
  const int w = t >> 6, lane = t & 63, quad = lane >> 4, l16 = lane & 15;
  const f32x4 zf = {0.f, 0.f, 0.f, 0.f};
  f32x4 acc[2][2] = {{zf, zf}, {zf, zf}};
#pragma unroll
  for (int kc = 0; kc < 4; ++kc) {
    bf16x8 a0 = *(const bf16x8*)&xh[l16][kc * 32 + quad * 8];
    bf16x8 a1 = *(const bf16x8*)&xh[16 + l16][kc * 32 + quad * 8];
    bf16x8 b0 = *(const bf16x8*)&WT[(size_t)(w * 32 + l16) * 128 + kc * 32 + quad * 8];
    bf16x8 b1 = *(const bf16x8*)&WT[(size_t)(w * 32 + 16 + l16) * 128 + kc * 32 + quad * 8];
    acc[0][0] = __builtin_amdgcn_mfma_f32_16x16x32_bf16(a0, b0, acc[0][0], 0, 0, 0);
    acc[0][1] = __builtin_amdgcn_mfma_f32_16x16x32_bf16(a0, b1, acc[0][1], 0, 0, 0);
    acc[1][0] = __builtin_amdgcn_mfma_f32_16x16x32_bf16(a1, b0, acc[1][0], 0, 0, 0);
    acc[1][1] = __builtin_amdgcn_mfma_f32_16x16x32_bf16(a1, b1, acc[1][1], 0, 0, 0);
  }
  if (mode == 0) {
    unsigned short* outh = (bid < 864) ? QPh : KPh;
    __syncthreads();                      // xh reused as output staging
#pragma unroll
    for (int mt = 0; mt < 2; ++mt)
#pragma unroll
      for (int nt = 0; nt < 2; ++nt) {
        int col = w * 32 + nt * 16 + l16;
        float bc = bias[col];
#pragma unroll
        for (int r = 0; r < 4; ++r)
          xh[mt * 16 + quad * 4 + r][col] = f2bf((acc[mt][nt][r] + bc) * osc);
      }
    __syncthreads();
#pragma unroll
    for (int i = 0; i < 2; ++i) {
      int s = i * 16 + (t >> 4), c8 = (t & 15) << 3;
      *(uint4*)&outh[((size_t)o * S + s0 + s) * 128 + c8] = *(uint4*)&xh[s][c8];
    }
  } else {
    const int b = o / 6, n = o % 6;
#pragma unroll
    for (int mt = 0; mt < 2; ++mt)
#pragma unroll
      for (int nt = 0; nt < 2; ++nt) {
        int col = w * 32 + nt * 16 + l16;
        int hh = col >> 5, dh = col & 31;
        float bc = bias[col];
        ushort4 pk;
        *(unsigned*)&pk.x = pkbf(acc[mt][nt][0] + bc, acc[mt][nt][1] + bc);
        *(unsigned*)&pk.z = pkbf(acc[mt][nt][2] + bc, acc[mt][nt][3] + bc);
        int s = n * 576 + s0 + mt * 16 + quad * 4;
        *(ushort4*)&VPTh[((size_t)(b * 4 + hh) * 32 + dh) * (size_t)NK_ + s] = pk;
      }
  }
}

// ---------------------------------------------------------------------------
// Kernel B: MFMA flash attention, software-pipelined. v2: the P-tile
// score->A-fragment rearrangement is done fully in-register with
// permlane32/16 swaps (T12) instead of an LDS round trip: removes the
// ds_write/lgkmcnt/ds_read chain, 1.6M bank conflicts, and 12KB of LDS.
// exp2 is the raw HW op (scores are tiny; no denorm fixup needed).
// MFMA cluster wrapped in s_setprio (independent waves, no barriers).
// Split-K is runtime-selected: sh=4 -> 16-way (grid 72*8*4), sh=3 -> 8-way.
// ---------------------------------------------------------------------------
__global__ __launch_bounds__(256) void k_attn_mfma(
    const unsigned short* __restrict__ QPh, const unsigned short* __restrict__ KPh,
    const unsigned short* __restrict__ VPTh, float* __restrict__ PO,
    float* __restrict__ Pl, int sh)
{
  __shared__ float ol[4][16][32];            // 8 KiB
  __shared__ float ll[4][2][4][16];          // 2 KiB
  const int t = threadIdx.x;
  const int w = t >> 6, lane = t & 63;
  const int quad = lane >> 4, l16 = lane & 15;
  const int qt = blockIdx.x % 72;
  const int rest = blockIdx.x / 72;
  const int bhx = rest & 7, ks = rest >> 3;
  const int bb = bhx >> 2, h = bhx & 3;
  const int q0 = qt << 5;

  const unsigned short* vbase = VPTh + (size_t)bhx * 32 * (size_t)NK_;
  const f32x4 zf = {0.f, 0.f, 0.f, 0.f};
  f32x4 o00 = zf, o01 = zf, o10 = zf, o11 = zf;
  float lsum0 = 0.f, lsum1 = 0.f;

  const int m8 = ks * 4 + w;                 // 0..4*nks-1
  int c0 = (108 * m8) >> sh, c1 = (108 * (m8 + 1)) >> sh;

  while (c0 < c1) {
    const int nn = c0 / 18;
    const int cend = min(c1, (nn + 1) * 18);
    const unsigned short* kb = &KPh[((size_t)(bb * 6 + nn) * K_) * 128 + h * 32];
    const unsigned short* qb = &QPh[((size_t)(bb * 6 + nn) * Q_ + q0) * 128 + h * 32];
    bf16x8 qc0 = *(const bf16x8*)&qb[(size_t)l16 * 128 + quad * 8];
    bf16x8 qc1 = *(const bf16x8*)&qb[(size_t)(16 + l16) * 128 + quad * 8];

    // prologue: load chunk c0, compute its scores
    int kl = (c0 - nn * 18) << 5;
    bf16x8 kf0 = *(const bf16x8*)&kb[(size_t)(kl + l16) * 128 + quad * 8];
    bf16x8 kf1 = *(const bf16x8*)&kb[(size_t)(kl + 16 + l16) * 128 + quad * 8];
    const unsigned short* vb = vbase + ((size_t)c0 << 5);
    bf16x8 pv0 = *(const bf16x8*)&vb[(size_t)l16 * NK_ + quad * 8];
    bf16x8 pv1 = *(const bf16x8*)&vb[(size_t)(16 + l16) * NK_ + quad * 8];
    f32x4 s00 = __builtin_amdgcn_mfma_f32_16x16x32_bf16(kf0, qc0, zf, 0, 0, 0);
    f32x4 s01 = __builtin_amdgcn_mfma_f32_16x16x32_bf16(kf1, qc0, zf, 0, 0, 0);
    f32x4 s10 = __builtin_amdgcn_mfma_f32_16x16x32_bf16(kf0, qc1, zf, 0, 0, 0);
    f32x4 s11 = __builtin_amdgcn_mfma_f32_16x16x32_bf16(kf1, qc1, zf, 0, 0, 0);

    for (int kc = c0; kc < cend; ++kc) {
      // issue loads for chunk kc+1 (unclamped prefetch; overrun reads stay
      // inside d_ws and are never consumed)
      const int kln = (kc + 1 - nn * 18) << 5;
      bf16x8 nk0 = *(const bf16x8*)&kb[(size_t)(kln + l16) * 128 + quad * 8];
      bf16x8 nk1 = *(const bf16x8*)&kb[(size_t)(kln + 16 + l16) * 128 + quad * 8];
      const unsigned short* vbn = vbase + ((size_t)(kc + 1) << 5);
      bf16x8 nv0 = *(const bf16x8*)&vbn[(size_t)l16 * NK_ + quad * 8];
      bf16x8 nv1 = *(const bf16x8*)&vbn[(size_t)(16 + l16) * NK_ + quad * 8];

      // exp2 of pending scores (raw HW op; |scores| small, no fixup needed)
      float a00 = __builtin_amdgcn_exp2f(s00.x), a01 = __builtin_amdgcn_exp2f(s00.y);
      float a02 = __builtin_amdgcn_exp2f(s00.z), a03 = __builtin_amdgcn_exp2f(s00.w);
      float a10 = __builtin_amdgcn_exp2f(s01.x), a11 = __builtin_amdgcn_exp2f(s01.y);
      float a12 = __builtin_amdgcn_exp2f(s01.z), a13 = __builtin_amdgcn_exp2f(s01.w);
      lsum0 += (a00 + a01 + a02 + a03) + (a10 + a11 + a12 + a13);
      float b00 = __builtin_amdgcn_exp2f(s10.x), b01 = __builtin_amdgcn_exp2f(s10.y);
      float b02 = __builtin_amdgcn_exp2f(s10.z), b03 = __builtin_amdgcn_exp2f(s10.w);
      float b10 = __builtin_amdgcn_exp2f(s11.x), b11 = __builtin_amdgcn_exp2f(s11.y);
      float b12 = __builtin_amdgcn_exp2f(s11.z), b13 = __builtin_amdgcn_exp2f(s11.w);
      lsum1 += (b00 + b01 + b02 + b03) + (b10 + b11 + b12 + b13);

      // pack: per quad q, A0=pk(k[4q],k[4q+1]) A1=pk(k[4q+2],k[4q+3]) (ktile0),
      //       B0/B1 same for ktile1 (k+16). Score D-layout: lane(quad,l16)
      //       holds k=4*quad+r, q=l16.
      unsigned xA0 = pkbf(a00, a01), xA1 = pkbf(a02, a03);
      unsigned xB0 = pkbf(a10, a11), xB1 = pkbf(a12, a13);
      unsigned yA0 = pkbf(b00, b01), yA1 = pkbf(b02, b03);
      unsigned yB0 = pkbf(b10, b11), yB1 = pkbf(b12, b13);
      // quad-exchange to PV A-fragment layout (lane needs k=8*quad..8*quad+7):
      // after pl32: A0={A0@q0,A0@q1,B0@q0,B0@q1}, B0={A0@q2,A0@q3,B0@q2,B0@q3}
      // after pl16: A0=D0, B0=D2 (and A1->D1, B1->D3)
      pl32sw(xA0, xB0); pl32sw(xA1, xB1);
      pl16sw(xA0, xB0); pl16sw(xA1, xB1);
      pl32sw(yA0, yB0); pl32sw(yA1, yB1);
      pl16sw(yA0, yB0); pl16sw(yA1, yB1);
      union { unsigned u[4]; bf16x8 v; } f0, f1;
      f0.u[0] = xA0; f0.u[1] = xA1; f0.u[2] = xB0; f0.u[3] = xB1;
      f1.u[0] = yA0; f1.u[1] = yA1; f1.u[2] = yB0; f1.u[3] = yB1;

      __builtin_amdgcn_s_setprio(1);
      o00 = __builtin_amdgcn_mfma_f32_16x16x32_bf16(f0.v, pv0, o00, 0, 0, 0);
      o01 = __builtin_amdgcn_mfma_f32_16x16x32_bf16(f0.v, pv1, o01, 0, 0, 0);
      o10 = __builtin_amdgcn_mfma_f32_16x16x32_bf16(f1.v, pv0, o10, 0, 0, 0);
      o11 = __builtin_amdgcn_mfma_f32_16x16x32_bf16(f1.v, pv1, o11, 0, 0, 0);
      // QK for chunk kc+1 (consumed next iteration; discarded at segment end)
      s00 = __builtin_amdgcn_mfma_f32_16x16x32_bf16(nk0, qc0, zf, 0, 0, 0);
      s01 = __builtin_amdgcn_mfma_f32_16x16x32_bf16(nk1, qc0, zf, 0, 0, 0);
      s10 = __builtin_amdgcn_mfma_f32_16x16x32_bf16(nk0, qc1, zf, 0, 0, 0);
      s11 = __builtin_amdgcn_mfma_f32_16x16x32_bf16(nk1, qc1, zf, 0, 0, 0);
      __builtin_amdgcn_s_setprio(0);
      pv0 = nv0; pv1 = nv1;
    }
    c0 = cend;
  }

  ll[w][0][quad][l16] = lsum0;
  ll[w][1][quad][l16] = lsum1;
#pragma unroll
  for (int tt = 0; tt < 2; ++tt) {
    __syncthreads();
    f32x4 t0 = tt ? o10 : o00;
    f32x4 t1 = tt ? o11 : o01;
#pragma unroll
    for (int r = 0; r < 4; ++r) {
      ol[w][quad * 4 + r][l16]      = t0[r];
      ol[w][quad * 4 + r][16 + l16] = t1[r];
    }
    __syncthreads();
    const int q = t >> 4, i16 = t & 15, dd = i16 << 1;
    float a0 = 0.f, a1 = 0.f;
#pragma unroll
    for (int ww = 0; ww < 4; ++ww) { a0 += ol[ww][q][dd]; a1 += ol[ww][q][dd + 1]; }
    float2 r2; r2.x = a0; r2.y = a1;
    *(float2*)&PO[(((size_t)ks * 8 + bhx) * Q_ + q0 + tt * 16 + q) * 32 + dd] = r2;
    if (i16 == 0) {
      float l = 0.f;
#pragma unroll
      for (int ww = 0; ww < 4; ++ww)
#pragma unroll
        for (int qq = 0; qq < 4; ++qq) l += ll[ww][tt][qq][q];
      Pl[((size_t)ks * 8 + bhx) * Q_ + q0 + tt * 16 + q] = l;
    }
  }
}

// ---------------------------------------------------------------------------
// Kernel C (fused tail, 512 threads, 16 rows/block, 288 blocks): nks-way
// ksplit-merge + out-proj + skip + preLN + fc1 + GELU + fc2 + residual
// + postLN + transposed store.
// ---------------------------------------------------------------------------
__global__ __launch_bounds__(512) void k_tail(
    const float* __restrict__ PO, const float* __restrict__ Pl,
    const unsigned short* __restrict__ WTp, const float* __restrict__ bp,
    const float* __restrict__ skip,
    const float* __restrict__ pre_g, const float* __restrict__ pre_b,
    const unsigned short* __restrict__ WT1, const float* __restrict__ b1,
    const unsigned short* __restrict__ WT2, const float* __restrict__ b2,
    const float* __restrict__ post_g, const float* __restrict__ post_b,
    float* __restrict__ out, int nks)
{
  __shared__ float xs[16][132];
  __shared__ unsigned short xh[16][136];
  __shared__ unsigned short hb[16][264];
  __shared__ float g1s[128], b1s[128], g2s[128], b2s[128];
  __shared__ float mu[16], rsd[16];
  const int t = threadIdx.x;
  const int row0 = blockIdx.x << 4;
  const int bb = row0 / Q_, hw0 = row0 % Q_;
  const int w = t >> 6, lane = t & 63, quad = lane >> 4, l16 = lane & 15;
  const f32x4 zf = {0.f, 0.f, 0.f, 0.f};

  if (t < 128) { g1s[t] = pre_g[t]; b1s[t] = pre_b[t]; g2s[t] = post_g[t]; b2s[t] = post_b[t]; }
  // --- stage 1: merge nks-way ksplit partials -> bf16 A-frags in xh
#pragma unroll
  for (int i = 0; i < 2; ++i) {
    int idx = t + 512 * i;               // 1024 pairs
    int s = idx >> 6, c2 = (idx & 63) << 1;
    int q = hw0 + s;
    int h = c2 >> 5, dh = c2 & 31;
    size_t bq = (size_t)(bb * 4 + h) * Q_ + q;
    size_t i0 = bq * 32 + dh;
    float px = 0.f, py = 0.f, l = 0.f;
    for (int p = 0; p < nks; ++p) {
      float2 pp = *(const float2*)&PO[(size_t)p * 589824 + i0];
      px += pp.x; py += pp.y;
      l += Pl[(size_t)p * 18432 + bq];
    }
    float inv = 1.f / l;
    *(unsigned*)&xh[s][c2] = pkbf(px * inv, py * inv);
  }
  __syncthreads();
  // --- stage 2: out-projection MFMA (wave w: cols w*16..w*16+15)
  {
    f32x4 acc = zf;
    const int col = w * 16 + l16;
#pragma unroll
    for (int kc = 0; kc < 4; ++kc) {
      bf16x8 a0 = *(const bf16x8*)&xh[l16][kc * 32 + quad * 8];
      bf16x8 b0 = *(const bf16x8*)&WTp[(size_t)col * 128 + kc * 32 + quad * 8];
      acc = __builtin_amdgcn_mfma_f32_16x16x32_bf16(a0, b0, acc, 0, 0, 0);
    }
    float bc = bp[col];
    float4 sk = *(const float4*)&skip[((size_t)bb * 128 + col) * Q_ + hw0 + quad * 4];
    xs[quad * 4 + 0][col] = acc[0] + bc + sk.x;
    xs[quad * 4 + 1][col] = acc[1] + bc + sk.y;
    xs[quad * 4 + 2][col] = acc[2] + bc + sk.z;
    xs[quad * 4 + 3][col] = acc[3] + bc + sk.w;
  }
  __syncthreads();
  // --- stage 3: preLN (32 lanes per row)
  {
    int s = t >> 5, lg = t & 31;
    float sum = 0.f, sq = 0.f;
    for (int c = lg; c < 128; c += 32) { float v = xs[s][c]; sum += v; sq += v * v; }
#pragma unroll
    for (int off = 16; off > 0; off >>= 1) {
      sum += __shfl_down(sum, off, 32);
      sq  += __shfl_down(sq,  off, 32);
    }
    if (lg == 0) {
      float mth = sum * 0.0078125f;
      float var = sq * 0.0078125f - mth * mth;
      mu[s] = mth; rsd[s] = rsqrtf(var + 1e-5f);
    }
  }
  __syncthreads();
#pragma unroll
  for (int i = 0; i < 2; ++i) {
    int idx = t + 512 * i;
    int s = idx >> 6, c2 = (idx & 63) << 1;
    float y0 = (xs[s][c2]     - mu[s]) * rsd[s] * g1s[c2]     + b1s[c2];
    float y1 = (xs[s][c2 + 1] - mu[s]) * rsd[s] * g1s[c2 + 1] + b1s[c2 + 1];
    xs[s][c2] = y0; xs[s][c2 + 1] = y1;
    *(unsigned*)&xh[s][c2] = pkbf(y0, y1);
  }
  __syncthreads();
  // --- stage 4: fc1 + GELU (wave w: cols w*32..w*32+31 of 256)
  {
#pragma unroll
    for (int nt = 0; nt < 2; ++nt) {
      const int col = w * 32 + nt * 16 + l16;
      f32x4 acc = zf;
#pragma unroll
      for (int kc = 0; kc < 4; ++kc) {
        bf16x8 a0 = *(const bf16x8*)&xh[l16][kc * 32 + quad * 8];
        bf16x8 b0 = *(const bf16x8*)&WT1[(size_t)col * 128 + kc * 32 + quad * 8];
        acc = __builtin_amdgcn_mfma_f32_16x16x32_bf16(a0, b0, acc, 0, 0, 0);
      }
      float bc = b1[col];
#pragma unroll
      for (int r = 0; r < 4; ++r) {
        float hx = acc[r] + bc;
        hb[quad * 4 + r][col] =
            f2bf(0.5f * hx * (1.f + erff(hx * 0.7071067811865476f)));
      }
    }
  }
  __syncthreads();
  // --- stage 5: fc2 (K=256) + residual z (wave w: cols w*16..w*16+15)
  {
    f32x4 acc = zf;
    const int col = w * 16 + l16;
#pragma unroll
    for (int kc = 0; kc < 8; ++kc) {
      bf16x8 a0 = *(const bf16x8*)&hb[l16][kc * 32 + quad * 8];
      bf16x8 b0 = *(const bf16x8*)&WT2[(size_t)col * 256 + kc * 32 + quad * 8];
      acc = __builtin_amdgcn_mfma_f32_16x16x32_bf16(a0, b0, acc, 0, 0, 0);
    }
    float bc = b2[col];
#pragma unroll
    for (int r = 0; r < 4; ++r) {
      int row = quad * 4 + r;
      xs[row][col] = acc[r] + bc + xs[row][col];
    }
  }
  __syncthreads();
  // --- stage 6: postLN + transposed store
  {
    int s = t >> 5, lg = t & 31;
    float sum = 0.f, sq = 0.f;
    for (int c = lg; c < 128; c += 32) { float v = xs[s][c]; sum += v; sq += v * v; }
#pragma unroll
    for (int off = 16; off > 0; off >>= 1) {
      sum += __shfl_down(sum, off, 32);
      sq  += __shfl_down(sq,  off, 32);
    }
    if (lg == 0) {
      float mth = sum * 0.0078125f;
      float var = sq * 0.0078125f - mth * mth;
      mu[s] = mth; rsd[s] = rsqrtf(var + 1e-5f);
    }
  }
  __syncthreads();
#pragma unroll
  for (int i = 0; i < 4; ++i) {
    int idx = t + 512 * i;
    int s = idx & 15, c = idx >> 4;
    out[(size_t)bb * (128 * (size_t)Q_) + (size_t)c * Q_ + hw0 + s] =
        (xs[s][c] - mu[s]) * rsd[s] * g2s[c] + b2s[c];
  }
}

// ---------------------------------------------------------------------------
extern "C" void kernel_launch(void* const* d_in, const int* in_sizes, int n_in,
                              void* d_out, int out_size, void* d_ws, size_t ws_size,
                              hipStream_t stream) {
  const float* q     = (const float*)d_in[0];
  const float* k     = (const float*)d_in[1];
  const float* v     = (const float*)d_in[2];
  const float* skip  = (const float*)d_in[3];
  const float* lnq_g = (const float*)d_in[4];
  const float* lnq_b = (const float*)d_in[5];
  const float* Wq    = (const float*)d_in[6];
  const float* bq    = (const float*)d_in[7];
  const float* lnk_g = (const float*)d_in[8];
  const float* lnk_b = (const float*)d_in[9];
  const float* Wk    = (const float*)d_in[10];
  const float* bk    = (const float*)d_in[11];
  const float* lnv_g = (const float*)d_in[12];
  const float* lnv_b = (const float*)d_in[13];
  const float* Wv    = (const float*)d_in[14];
  const float* bvv   = (const float*)d_in[15];
  const float* Wp    = (const float*)d_in[16];
  const float* bp    = (const float*)d_in[17];
  const float* pre_g = (const float*)d_in[18];
  const float* pre_b = (const float*)d_in[19];
  const float* W1    = (const float*)d_in[20];
  const float* b1    = (const float*)d_in[21];
  const float* W2    = (const float*)d_in[22];
  const float* b2    = (const float*)d_in[23];
  const float* post_g= (const float*)d_in[24];
  const float* post_b= (const float*)d_in[25];
  float* out = (float*)d_out;

  // Workspace layout. nks=4 needs 20,611,072 B; nks=2 needs 15,740,928 B.
  int nks = 2, sh = 3;
  if (ws_size >= (size_t)20611072) { nks = 4; sh = 4; }
  unsigned short* QPh  = (unsigned short*)d_ws;        // 3,538,944 h
  unsigned short* KPh  = QPh + 3538944;                //   884,736 h
  unsigned short* VPTh = KPh + 884736;                 //   884,736 h
  float* PO  = (float*)(VPTh + 884736);                // nks*589,824 f
  float* Pl  = PO + (size_t)nks * 589824;              // nks*18,432 f
  unsigned short* WTq = (unsigned short*)(Pl + (size_t)nks * 18432);
  unsigned short* WTk = WTq + 16384;                   //    16,384 h
  unsigned short* WTv = WTk + 16384;                   //    16,384 h
  unsigned short* WTp = WTv + 16384;                   //    16,384 h
  unsigned short* WT1 = WTp + 16384;                   //    32,768 h
  unsigned short* WT2 = WT1 + 32768;                   //    32,768 h

  k_prep_wt<<<dim3(128), dim3(256), 0, stream>>>(Wq, Wk, Wv, Wp, W1, W2,
                                                 WTq, WTk, WTv, WTp, WT1, WT2);
  k_ln_proj_all<<<dim3(1296), dim3(256), 0, stream>>>(
      q, k, v, lnq_g, lnq_b, lnk_g, lnk_b, lnv_g, lnv_b,
      WTq, WTk, WTv, bq, bk, bvv, QPh, KPh, VPTh);
  k_attn_mfma<<<dim3(72 * 8 * nks), dim3(256), 0, stream>>>(QPh, KPh, VPTh, PO, Pl, sh);
  k_tail<<<dim3(288), dim3(512), 0, stream>>>(PO, Pl, WTp, bp, skip,
                                              pre_g, pre_b, WT1, b1, WT2, b2,
                                              post_g, post_b, out, nks);
}

// Round 2
// 163.846 us; speedup vs baseline: 1.0910x; 1.0910x over previous
//
#include <hip/hip_runtime.h>
#include <cmath>

// Shapes (fixed for this problem)
#define B_    2
#define N_    6
#define D_    128
#define Q_    2304      // 48*48
#define K_    576       // 24*24
#define NK_   3456      // N_*K_
#define HEADS_ 4
#define DH_   32
#define SCALE_ 0.17677669529663687f        // 1/sqrt(32)
#define SCLOG2E_ 0.25504672615621814f      // SCALE * log2(e)

typedef __attribute__((ext_vector_type(8))) short bf16x8;
typedef __attribute__((ext_vector_type(4))) float f32x4;

#if defined(__has_builtin)
#if __has_builtin(__builtin_amdgcn_cvt_pk_bf16_f32)
#define HAS_PK_BF16 1
#endif
#endif

static __device__ __forceinline__ unsigned short f2bf(float f) {
  union { float f; unsigned u; } x; x.f = f;
  unsigned u = x.u + 0x7fffu + ((x.u >> 16) & 1u);   // RNE
  return (unsigned short)(u >> 16);
}
static __device__ __forceinline__ unsigned pkbf(float a, float b) {
#ifdef HAS_PK_BF16
  typedef __attribute__((ext_vector_type(2))) __bf16 vbf2;
  union { vbf2 v; unsigned u; } cv;
  cv.v = __builtin_amdgcn_cvt_pk_bf16_f32(a, b);   // RNE pack, 1 inst
  return cv.u;
#else
  return (unsigned)f2bf(a) | ((unsigned)f2bf(b) << 16);
#endif
}

// permlane swaps (gfx950): both operands are read-modify-write.
static __device__ __forceinline__ void pl32sw(unsigned &a, unsigned &b) {
  asm("v_permlane32_swap_b32 %0, %1" : "+v"(a), "+v"(b));
}
static __device__ __forceinline__ void pl16sw(unsigned &a, unsigned &b) {
  asm("v_permlane16_swap_b32 %0, %1" : "+v"(a), "+v"(b));
}

// ---------------------------------------------------------------------------
// Kernel P: transpose+convert all weights to bf16 WT[n][k] (MFMA B-frag
// layout). 128 blocks, one 32x32 tile each. Also zeroes PO/Pl (atomic
// accumulation targets for the attention kernel).
// ---------------------------------------------------------------------------
__global__ __launch_bounds__(256) void k_prep_wt(
    const float* __restrict__ Wq, const float* __restrict__ Wk,
    const float* __restrict__ Wv, const float* __restrict__ Wp,
    const float* __restrict__ W1, const float* __restrict__ W2,
    unsigned short* __restrict__ WTq, unsigned short* __restrict__ WTk,
    unsigned short* __restrict__ WTv, unsigned short* __restrict__ WTp,
    unsigned short* __restrict__ WT1, unsigned short* __restrict__ WT2,
    float* __restrict__ Z, int zn)
{
  __shared__ float tile[32][33];
  const int wb = blockIdx.x, t = threadIdx.x;
  // zero PO/Pl (independent of the transpose work)
  {
    const float4 z4 = {0.f, 0.f, 0.f, 0.f};
    for (int i = wb * 256 + t; i < zn; i += 128 * 256)
      ((float4*)Z)[i] = z4;
  }
  const float* src; unsigned short* dst; int Kd, J, tl;
  if      (wb < 16) { src = Wq; dst = WTq; Kd = 128; J = 128; tl = wb; }
  else if (wb < 32) { src = Wk; dst = WTk; Kd = 128; J = 128; tl = wb - 16; }
  else if (wb < 48) { src = Wv; dst = WTv; Kd = 128; J = 128; tl = wb - 32; }
  else if (wb < 64) { src = Wp; dst = WTp; Kd = 128; J = 128; tl = wb - 48; }
  else if (wb < 96) { src = W1; dst = WT1; Kd = 128; J = 256; tl = wb - 64; }
  else              { src = W2; dst = WT2; Kd = 256; J = 128; tl = wb - 96; }
  const int njt = J >> 5;
  const int tj = tl % njt, tk = tl / njt;
#pragma unroll
  for (int i = 0; i < 4; ++i) {
    int idx = t + 256 * i;
    int r = idx >> 5, c = idx & 31;
    tile[r][c] = src[(size_t)(tk * 32 + r) * J + tj * 32 + c];
  }
  __syncthreads();
#pragma unroll
  for (int i = 0; i < 2; ++i) {
    int idx = t + 256 * i;               // 512 pairs
    int rr = idx >> 4, c2 = (idx & 15) << 1;
    *(unsigned*)&dst[(size_t)(tj * 32 + rr) * Kd + tk * 32 + c2] =
        pkbf(tile[c2][rr], tile[c2 + 1][rr]);
  }
}

// ---------------------------------------------------------------------------
// Kernel A: fused q/k/v LN + MFMA projection (single dispatch, 1296 blocks).
// Q output is pre-scaled by SCALE*log2(e) so attention uses native exp2.
// ---------------------------------------------------------------------------
__global__ __launch_bounds__(256) void k_ln_proj_all(
    const float* __restrict__ qin, const float* __restrict__ kin,
    const float* __restrict__ vin,
    const float* __restrict__ lnq_g, const float* __restrict__ lnq_b,
    const float* __restrict__ lnk_g, const float* __restrict__ lnk_b,
    const float* __restrict__ lnv_g, const float* __restrict__ lnv_b,
    const unsigned short* __restrict__ WTq, const unsigned short* __restrict__ WTk,
    const unsigned short* __restrict__ WTv,
    const float* __restrict__ bq, const float* __restrict__ bk,
    const float* __restrict__ bv,
    unsigned short* __restrict__ QPh, unsigned short* __restrict__ KPh,
    unsigned short* __restrict__ VPTh)
{
  __shared__ float xs[32][132];
  __shared__ unsigned short xh[32][136];
  __shared__ float gs[128], bs[128];
  __shared__ float mu[32], rsd[32];
  const int t = threadIdx.x;
  const int bid = blockIdx.x;

  const float* x; const unsigned short* WT; const float* g; const float* bl;
  const float* bias; int S, blk, mode; float osc;
  if (bid < 864)       { mode = 0; blk = bid;        x = qin; WT = WTq; g = lnq_g; bl = lnq_b; bias = bq; S = Q_; osc = SCLOG2E_; }
  else if (bid < 1080) { mode = 0; blk = bid - 864;  x = kin; WT = WTk; g = lnk_g; bl = lnk_b; bias = bk; S = K_; osc = 1.0f; }
  else                 { mode = 1; blk = bid - 1080; x = vin; WT = WTv; g = lnv_g; bl = lnv_b; bias = bv; S = K_; osc = 1.0f; }
  const int ntile = S >> 5;
  const int o  = blk / ntile;
  const int s0 = (blk % ntile) << 5;

  if (t < 128) { gs[t] = g[t]; bs[t] = bl[t]; }
  const float* xb = x + (size_t)o * 128 * (size_t)S + s0;
#pragma unroll
  for (int i = 0; i < 4; ++i) {
    int idx = t + 256 * i;
    int c = idx >> 3, s4 = (idx & 7) << 2;
    float4 xv = *(const float4*)&xb[(size_t)c * S + s4];
    xs[s4 + 0][c] = xv.x; xs[s4 + 1][c] = xv.y;
    xs[s4 + 2][c] = xv.z; xs[s4 + 3][c] = xv.w;
  }
  __syncthreads();
  {
    int s = t >> 3, l8 = t & 7;
    float sum = 0.f, sq = 0.f;
    for (int c = l8; c < 128; c += 8) { float v = xs[s][c]; sum += v; sq += v * v; }
#pragma unroll
    for (int off = 4; off > 0; off >>= 1) {
      sum += __shfl_down(sum, off, 8);
      sq  += __shfl_down(sq,  off, 8);
    }
    if (l8 == 0) {
      float mth = sum * 0.0078125f;
      float var = sq * 0.0078125f - mth * mth;
      mu[s] = mth; rsd[s] = rsqrtf(var + 1e-5f);
    }
  }
  __syncthreads();
#pragma unroll
  for (int i = 0; i < 8; ++i) {
    int idx = t + 256 * i;               // 2048 pairs
    int s = idx >> 6, c2 = (idx & 63) << 1;
    float y0 = (xs[s][c2]     - mu[s]) * rsd[s] * gs[c2]     + bs[c2];
    float y1 = (xs[s][c2 + 1] - mu[s]) * rsd[s] * gs[c2 + 1] + bs[c2 + 1];
    *(unsigned*)&xh[s][c2] = pkbf(y0, y1);
  }
  __syncthreads();
  const int w = t >> 6, lane = t & 63, quad = lane >> 4, l16 = lane & 15;
  const f32x4 zf = {0.f, 0.f, 0.f, 0.f};
  f32x4 acc[2][2] = {{zf, zf}, {zf, zf}};
#pragma unroll
  for (int kc = 0; kc < 4; ++kc) {
    bf16x8 a0 = *(const bf16x8*)&xh[l16][kc * 32 + quad * 8];
    bf16x8 a1 = *(const bf16x8*)&xh[16 + l16][kc * 32 + quad * 8];
    bf16x8 b0 = *(const bf16x8*)&WT[(size_t)(w * 32 + l16) * 128 + kc * 32 + quad * 8];
    bf16x8 b1 = *(const bf16x8*)&WT[(size_t)(w * 32 + 16 + l16) * 128 + kc * 32 + quad * 8];
    acc[0][0] = __builtin_amdgcn_mfma_f32_16x16x32_bf16(a0, b0, acc[0][0], 0, 0, 0);
    acc[0][1] = __builtin_amdgcn_mfma_f32_16x16x32_bf16(a0, b1, acc[0][1], 0, 0, 0);
    acc[1][0] = __builtin_amdgcn_mfma_f32_16x16x32_bf16(a1, b0, acc[1][0], 0, 0, 0);
    acc[1][1] = __builtin_amdgcn_mfma_f32_16x16x32_bf16(a1, b1, acc[1][1], 0, 0, 0);
  }
  if (mode == 0) {
    unsigned short* outh = (bid < 864) ? QPh : KPh;
    __syncthreads();                      // xh reused as output staging
#pragma unroll
    for (int mt = 0; mt < 2; ++mt)
#pragma unroll
      for (int nt = 0; nt < 2; ++nt) {
        int col = w * 32 + nt * 16 + l16;
        float bc = bias[col];
#pragma unroll
        for (int r = 0; r < 4; ++r)
          xh[mt * 16 + quad * 4 + r][col] = f2bf((acc[mt][nt][r] + bc) * osc);
      }
    __syncthreads();
#pragma unroll
    for (int i = 0; i < 2; ++i) {
      int s = i * 16 + (t >> 4), c8 = (t & 15) << 3;
      *(uint4*)&outh[((size_t)o * S + s0 + s) * 128 + c8] = *(uint4*)&xh[s][c8];
    }
  } else {
    const int b = o / 6, n = o % 6;
#pragma unroll
    for (int mt = 0; mt < 2; ++mt)
#pragma unroll
      for (int nt = 0; nt < 2; ++nt) {
        int col = w * 32 + nt * 16 + l16;
        int hh = col >> 5, dh = col & 31;
        float bc = bias[col];
        ushort4 pk;
        *(unsigned*)&pk.x = pkbf(acc[mt][nt][0] + bc, acc[mt][nt][1] + bc);
        *(unsigned*)&pk.z = pkbf(acc[mt][nt][2] + bc, acc[mt][nt][3] + bc);
        int s = n * 576 + s0 + mt * 16 + quad * 4;
        *(ushort4*)&VPTh[((size_t)(b * 4 + hh) * 32 + dh) * (size_t)NK_ + s] = pk;
      }
  }
}

// ---------------------------------------------------------------------------
// Kernel B v3: block = (q-group, bhx, nn). 4 waves share the K/V chunk
// stream via LDS (staged once per block, not once per wave -> 4x fewer
// global vmem instructions); each wave owns one 32-row q-tile and runs the
// full 18-chunk segment of view nn, so its accumulators are complete for
// (q-tile, nn). Partials merged across the 6 nn-blocks by atomicAdd into
// PO/Pl (zeroed in k_prep_wt). Depth-2 staging prefetch: the ds_write at
// the top of iter kc uses data global-loaded in iter kc-1 (vmcnt fully
// covered). K/V LDS tiles use a 2-bit XOR slot swizzle -> 2-way bank
// aliasing only (free). In-register P rearrangement via permlane swaps.
// Grid: 18 x 8 x 6 = 864 blocks.
// ---------------------------------------------------------------------------
__global__ __launch_bounds__(256) void k_attn_mfma(
    const unsigned short* __restrict__ QPh, const unsigned short* __restrict__ KPh,
    const unsigned short* __restrict__ VPTh, float* __restrict__ PO,
    float* __restrict__ Pl)
{
  // [buf][ K tile 1024h | V tile 1024h ]; row*32 + swizzled-slot*8 (shorts)
  __shared__ __align__(16) unsigned short smem[2][2048];   // 8 KiB
  const int t = threadIdx.x;
  const int w = t >> 6, lane = t & 63;
  const int quad = lane >> 4, l16 = lane & 15;
  const int qg  = blockIdx.x % 18;
  const int rest = blockIdx.x / 18;
  const int bhx = rest & 7, nn = rest >> 3;          // nn = 0..5
  const int bb = bhx >> 2, h = bhx & 3;
  const int q0 = (qg * 4 + w) << 5;                  // per-wave q-tile

  const unsigned short* kb = KPh + ((size_t)(bb * 6 + nn) * K_) * 128 + h * 32;
  const unsigned short* qb = QPh + ((size_t)(bb * 6 + nn) * Q_ + q0) * 128 + h * 32;
  const unsigned short* vb = VPTh + (size_t)bhx * 32 * (size_t)NK_ + (size_t)nn * 18 * 32;

  // per-wave Q fragments (loaded once)
  bf16x8 qc0 = *(const bf16x8*)&qb[(size_t)l16 * 128 + quad * 8];
  bf16x8 qc1 = *(const bf16x8*)&qb[(size_t)(16 + l16) * 128 + quad * 8];

  // staging: wave 0/1 -> K rows 0-15/16-31; wave 2/3 -> V rows 0-15/16-31.
  const int row16 = l16 + ((w & 1) << 4);
  const int xsl = (quad ^ ((l16 >> 1) & 3)) << 3;    // swizzled slot (shorts)
  const unsigned short* sbase = (w < 2)
      ? kb + (size_t)row16 * 128 + quad * 8
      : vb + (size_t)row16 * NK_ + quad * 8;
  const int sstride = (w < 2) ? 4096 : 32;           // shorts per chunk step
  const int wdst = ((w >= 2) ? 1024 : 0) + row16 * 32 + xsl;

  const f32x4 zf = {0.f, 0.f, 0.f, 0.f};
  f32x4 o00 = zf, o01 = zf, o10 = zf, o11 = zf;
  float lsum0 = 0.f, lsum1 = 0.f;

  // prologue: stage chunk 0 into buf0; preload chunk 1 into regs
  uint4 st0 = *(const uint4*)&sbase[0];
  uint4 stn = *(const uint4*)&sbase[sstride];
  *(uint4*)&smem[0][wdst] = st0;
  __syncthreads();

#pragma unroll 2
  for (int kc = 0; kc < 18; ++kc) {
    const int buf = kc & 1;
    // write next buffer early (data loaded one iteration ago; safe: all
    // waves' reads of buf^1 completed before the barrier ending kc-1)
    if (kc < 17) *(uint4*)&smem[buf ^ 1][wdst] = stn;
    // issue global load for chunk kc+2
    if (kc < 16) stn = *(const uint4*)&sbase[(size_t)(kc + 2) * sstride];

    const unsigned short* sb = &smem[buf][0];
    bf16x8 kf0 = *(const bf16x8*)&sb[l16 * 32 + xsl];
    bf16x8 kf1 = *(const bf16x8*)&sb[(16 + l16) * 32 + xsl];
    bf16x8 pv0 = *(const bf16x8*)&sb[1024 + l16 * 32 + xsl];
    bf16x8 pv1 = *(const bf16x8*)&sb[1024 + (16 + l16) * 32 + xsl];

    __builtin_amdgcn_s_setprio(1);
    f32x4 s00 = __builtin_amdgcn_mfma_f32_16x16x32_bf16(kf0, qc0, zf, 0, 0, 0);
    f32x4 s01 = __builtin_amdgcn_mfma_f32_16x16x32_bf16(kf1, qc0, zf, 0, 0, 0);
    f32x4 s10 = __builtin_amdgcn_mfma_f32_16x16x32_bf16(kf0, qc1, zf, 0, 0, 0);
    f32x4 s11 = __builtin_amdgcn_mfma_f32_16x16x32_bf16(kf1, qc1, zf, 0, 0, 0);

    // exp2 in log2 domain (Q pre-scaled; |scores| small, raw HW op exact)
    float a00 = __builtin_amdgcn_exp2f(s00.x), a01 = __builtin_amdgcn_exp2f(s00.y);
    float a02 = __builtin_amdgcn_exp2f(s00.z), a03 = __builtin_amdgcn_exp2f(s00.w);
    float a10 = __builtin_amdgcn_exp2f(s01.x), a11 = __builtin_amdgcn_exp2f(s01.y);
    float a12 = __builtin_amdgcn_exp2f(s01.z), a13 = __builtin_amdgcn_exp2f(s01.w);
    lsum0 += (a00 + a01 + a02 + a03) + (a10 + a11 + a12 + a13);
    float b00 = __builtin_amdgcn_exp2f(s10.x), b01 = __builtin_amdgcn_exp2f(s10.y);
    float b02 = __builtin_amdgcn_exp2f(s10.z), b03 = __builtin_amdgcn_exp2f(s10.w);
    float b10 = __builtin_amdgcn_exp2f(s11.x), b11 = __builtin_amdgcn_exp2f(s11.y);
    float b12 = __builtin_amdgcn_exp2f(s11.z), b13 = __builtin_amdgcn_exp2f(s11.w);
    lsum1 += (b00 + b01 + b02 + b03) + (b10 + b11 + b12 + b13);

    // pack + quad-exchange to PV A-fragment layout (verified in round 1)
    unsigned xA0 = pkbf(a00, a01), xA1 = pkbf(a02, a03);
    unsigned xB0 = pkbf(a10, a11), xB1 = pkbf(a12, a13);
    unsigned yA0 = pkbf(b00, b01), yA1 = pkbf(b02, b03);
    unsigned yB0 = pkbf(b10, b11), yB1 = pkbf(b12, b13);
    pl32sw(xA0, xB0); pl32sw(xA1, xB1);
    pl16sw(xA0, xB0); pl16sw(xA1, xB1);
    pl32sw(yA0, yB0); pl32sw(yA1, yB1);
    pl16sw(yA0, yB0); pl16sw(yA1, yB1);
    union { unsigned u[4]; bf16x8 v; } f0, f1;
    f0.u[0] = xA0; f0.u[1] = xA1; f0.u[2] = xB0; f0.u[3] = xB1;
    f1.u[0] = yA0; f1.u[1] = yA1; f1.u[2] = yB0; f1.u[3] = yB1;

    o00 = __builtin_amdgcn_mfma_f32_16x16x32_bf16(f0.v, pv0, o00, 0, 0, 0);
    o01 = __builtin_amdgcn_mfma_f32_16x16x32_bf16(f0.v, pv1, o01, 0, 0, 0);
    o10 = __builtin_amdgcn_mfma_f32_16x16x32_bf16(f1.v, pv0, o10, 0, 0, 0);
    o11 = __builtin_amdgcn_mfma_f32_16x16x32_bf16(f1.v, pv1, o11, 0, 0, 0);
    __builtin_amdgcn_s_setprio(0);
    __syncthreads();
  }

  // epilogue: reduce lsum across quads (k-slices) -> full row sums
  lsum0 += __shfl_xor(lsum0, 16);
  lsum0 += __shfl_xor(lsum0, 32);
  lsum1 += __shfl_xor(lsum1, 16);
  lsum1 += __shfl_xor(lsum1, 32);
  if (lane < 16) {
    atomicAdd(&Pl[(size_t)bhx * Q_ + q0 + lane], lsum0);
    atomicAdd(&Pl[(size_t)bhx * Q_ + q0 + 16 + lane], lsum1);
  }
  float* pob = PO + ((size_t)bhx * Q_ + q0) * 32;
#pragma unroll
  for (int r = 0; r < 4; ++r) {
    atomicAdd(&pob[(quad * 4 + r) * 32 + l16],           o00[r]);
    atomicAdd(&pob[(quad * 4 + r) * 32 + 16 + l16],      o01[r]);
    atomicAdd(&pob[(16 + quad * 4 + r) * 32 + l16],      o10[r]);
    atomicAdd(&pob[(16 + quad * 4 + r) * 32 + 16 + l16], o11[r]);
  }
}

// ---------------------------------------------------------------------------
// Kernel C (fused tail, 512 threads, 16 rows/block, 288 blocks): merged-PO
// normalize + out-proj + skip + preLN + fc1 + GELU + fc2 + residual
// + postLN + transposed store.
// ---------------------------------------------------------------------------
__global__ __launch_bounds__(512) void k_tail(
    const float* __restrict__ PO, const float* __restrict__ Pl,
    const unsigned short* __restrict__ WTp, const float* __restrict__ bp,
    const float* __restrict__ skip,
    const float* __restrict__ pre_g, const float* __restrict__ pre_b,
    const unsigned short* __restrict__ WT1, const float* __restrict__ b1,
    const unsigned short* __restrict__ WT2, const float* __restrict__ b2,
    const float* __restrict__ post_g, const float* __restrict__ post_b,
    float* __restrict__ out)
{
  __shared__ float xs[16][132];
  __shared__ unsigned short xh[16][136];
  __shared__ unsigned short hb[16][264];
  __shared__ float g1s[128], b1s[128], g2s[128], b2s[128];
  __shared__ float mu[16], rsd[16];
  const int t = threadIdx.x;
  const int row0 = blockIdx.x << 4;
  const int bb = row0 / Q_, hw0 = row0 % Q_;
  const int w = t >> 6, lane = t & 63, quad = lane >> 4, l16 = lane & 15;
  const f32x4 zf = {0.f, 0.f, 0.f, 0.f};

  if (t < 128) { g1s[t] = pre_g[t]; b1s[t] = pre_b[t]; g2s[t] = post_g[t]; b2s[t] = post_b[t]; }
  // --- stage 1: normalize merged PO -> bf16 A-frags in xh
#pragma unroll
  for (int i = 0; i < 2; ++i) {
    int idx = t + 512 * i;               // 1024 pairs
    int s = idx >> 6, c2 = (idx & 63) << 1;
    int q = hw0 + s;
    int h = c2 >> 5, dh = c2 & 31;
    size_t bq = (size_t)(bb * 4 + h) * Q_ + q;
    size_t i0 = bq * 32 + dh;
    float2 pp = *(const float2*)&PO[i0];
    float inv = 1.f / Pl[bq];
    *(unsigned*)&xh[s][c2] = pkbf(pp.x * inv, pp.y * inv);
  }
  __syncthreads();
  // --- stage 2: out-projection MFMA (wave w: cols w*16..w*16+15)
  {
    f32x4 acc = zf;
    const int col = w * 16 + l16;
#pragma unroll
    for (int kc = 0; kc < 4; ++kc) {
      bf16x8 a0 = *(const bf16x8*)&xh[l16][kc * 32 + quad * 8];
      bf16x8 b0 = *(const bf16x8*)&WTp[(size_t)col * 128 + kc * 32 + quad * 8];
      acc = __builtin_amdgcn_mfma_f32_16x16x32_bf16(a0, b0, acc, 0, 0, 0);
    }
    float bc = bp[col];
    float4 sk = *(const float4*)&skip[((size_t)bb * 128 + col) * Q_ + hw0 + quad * 4];
    xs[quad * 4 + 0][col] = acc[0] + bc + sk.x;
    xs[quad * 4 + 1][col] = acc[1] + bc + sk.y;
    xs[quad * 4 + 2][col] = acc[2] + bc + sk.z;
    xs[quad * 4 + 3][col] = acc[3] + bc + sk.w;
  }
  __syncthreads();
  // --- stage 3: preLN (32 lanes per row)
  {
    int s = t >> 5, lg = t & 31;
    float sum = 0.f, sq = 0.f;
    for (int c = lg; c < 128; c += 32) { float v = xs[s][c]; sum += v; sq += v * v; }
#pragma unroll
    for (int off = 16; off > 0; off >>= 1) {
      sum += __shfl_down(sum, off, 32);
      sq  += __shfl_down(sq,  off, 32);
    }
    if (lg == 0) {
      float mth = sum * 0.0078125f;
      float var = sq * 0.0078125f - mth * mth;
      mu[s] = mth; rsd[s] = rsqrtf(var + 1e-5f);
    }
  }
  __syncthreads();
#pragma unroll
  for (int i = 0; i < 2; ++i) {
    int idx = t + 512 * i;
    int s = idx >> 6, c2 = (idx & 63) << 1;
    float y0 = (xs[s][c2]     - mu[s]) * rsd[s] * g1s[c2]     + b1s[c2];
    float y1 = (xs[s][c2 + 1] - mu[s]) * rsd[s] * g1s[c2 + 1] + b1s[c2 + 1];
    xs[s][c2] = y0; xs[s][c2 + 1] = y1;
    *(unsigned*)&xh[s][c2] = pkbf(y0, y1);
  }
  __syncthreads();
  // --- stage 4: fc1 + GELU (wave w: cols w*32..w*32+31 of 256)
  {
#pragma unroll
    for (int nt = 0; nt < 2; ++nt) {
      const int col = w * 32 + nt * 16 + l16;
      f32x4 acc = zf;
#pragma unroll
      for (int kc = 0; kc < 4; ++kc) {
        bf16x8 a0 = *(const bf16x8*)&xh[l16][kc * 32 + quad * 8];
        bf16x8 b0 = *(const bf16x8*)&WT1[(size_t)col * 128 + kc * 32 + quad * 8];
        acc = __builtin_amdgcn_mfma_f32_16x16x32_bf16(a0, b0, acc, 0, 0, 0);
      }
      float bc = b1[col];
#pragma unroll
      for (int r = 0; r < 4; ++r) {
        float hx = acc[r] + bc;
        hb[quad * 4 + r][col] =
            f2bf(0.5f * hx * (1.f + erff(hx * 0.7071067811865476f)));
      }
    }
  }
  __syncthreads();
  // --- stage 5: fc2 (K=256) + residual z (wave w: cols w*16..w*16+15)
  {
    f32x4 acc = zf;
    const int col = w * 16 + l16;
#pragma unroll
    for (int kc = 0; kc < 8; ++kc) {
      bf16x8 a0 = *(const bf16x8*)&hb[l16][kc * 32 + quad * 8];
      bf16x8 b0 = *(const bf16x8*)&WT2[(size_t)col * 256 + kc * 32 + quad * 8];
      acc = __builtin_amdgcn_mfma_f32_16x16x32_bf16(a0, b0, acc, 0, 0, 0);
    }
    float bc = b2[col];
#pragma unroll
    for (int r = 0; r < 4; ++r) {
      int row = quad * 4 + r;
      xs[row][col] = acc[r] + bc + xs[row][col];
    }
  }
  __syncthreads();
  // --- stage 6: postLN + transposed store
  {
    int s = t >> 5, lg = t & 31;
    float sum = 0.f, sq = 0.f;
    for (int c = lg; c < 128; c += 32) { float v = xs[s][c]; sum += v; sq += v * v; }
#pragma unroll
    for (int off = 16; off > 0; off >>= 1) {
      sum += __shfl_down(sum, off, 32);
      sq  += __shfl_down(sq,  off, 32);
    }
    if (lg == 0) {
      float mth = sum * 0.0078125f;
      float var = sq * 0.0078125f - mth * mth;
      mu[s] = mth; rsd[s] = rsqrtf(var + 1e-5f);
    }
  }
  __syncthreads();
#pragma unroll
  for (int i = 0; i < 4; ++i) {
    int idx = t + 512 * i;
    int s = idx & 15, c = idx >> 4;
    out[(size_t)bb * (128 * (size_t)Q_) + (size_t)c * Q_ + hw0 + s] =
        (xs[s][c] - mu[s]) * rsd[s] * g2s[c] + b2s[c];
  }
}

// ---------------------------------------------------------------------------
extern "C" void kernel_launch(void* const* d_in, const int* in_sizes, int n_in,
                              void* d_out, int out_size, void* d_ws, size_t ws_size,
                              hipStream_t stream) {
  const float* q     = (const float*)d_in[0];
  const float* k     = (const float*)d_in[1];
  const float* v     = (const float*)d_in[2];
  const float* skip  = (const float*)d_in[3];
  const float* lnq_g = (const float*)d_in[4];
  const float* lnq_b = (const float*)d_in[5];
  const float* Wq    = (const float*)d_in[6];
  const float* bq    = (const float*)d_in[7];
  const float* lnk_g = (const float*)d_in[8];
  const float* lnk_b = (const float*)d_in[9];
  const float* Wk    = (const float*)d_in[10];
  const float* bk    = (const float*)d_in[11];
  const float* lnv_g = (const float*)d_in[12];
  const float* lnv_b = (const float*)d_in[13];
  const float* Wv    = (const float*)d_in[14];
  const float* bvv   = (const float*)d_in[15];
  const float* Wp    = (const float*)d_in[16];
  const float* bp    = (const float*)d_in[17];
  const float* pre_g = (const float*)d_in[18];
  const float* pre_b = (const float*)d_in[19];
  const float* W1    = (const float*)d_in[20];
  const float* b1    = (const float*)d_in[21];
  const float* W2    = (const float*)d_in[22];
  const float* b2    = (const float*)d_in[23];
  const float* post_g= (const float*)d_in[24];
  const float* post_b= (const float*)d_in[25];
  float* out = (float*)d_out;

  // Workspace layout (~13.3 MB)
  unsigned short* QPh  = (unsigned short*)d_ws;        // 3,538,944 h
  unsigned short* KPh  = QPh + 3538944;                //   884,736 h
  unsigned short* VPTh = KPh + 884736;                 //   884,736 h
  float* PO  = (float*)(VPTh + 884736);                //   589,824 f (merged)
  float* Pl  = PO + 589824;                            //    18,432 f
  unsigned short* WTq = (unsigned short*)(Pl + 18432); //    16,384 h
  unsigned short* WTk = WTq + 16384;                   //    16,384 h
  unsigned short* WTv = WTk + 16384;                   //    16,384 h
  unsigned short* WTp = WTv + 16384;                   //    16,384 h
  unsigned short* WT1 = WTp + 16384;                   //    32,768 h
  unsigned short* WT2 = WT1 + 32768;                   //    32,768 h
  const int zn = (589824 + 18432) / 4;                 // float4s to zero

  k_prep_wt<<<dim3(128), dim3(256), 0, stream>>>(Wq, Wk, Wv, Wp, W1, W2,
                                                 WTq, WTk, WTv, WTp, WT1, WT2,
                                                 PO, zn);
  k_ln_proj_all<<<dim3(1296), dim3(256), 0, stream>>>(
      q, k, v, lnq_g, lnq_b, lnk_g, lnk_b, lnv_g, lnv_b,
      WTq, WTk, WTv, bq, bk, bvv, QPh, KPh, VPTh);
  k_attn_mfma<<<dim3(18 * 8 * 6), dim3(256), 0, stream>>>(QPh, KPh, VPTh, PO, Pl);
  k_tail<<<dim3(288), dim3(512), 0, stream>>>(PO, Pl, WTp, bp, skip,
                                              pre_g, pre_b, WT1, b1, WT2, b2,
                                              post_g, post_b, out);
}